// Round 14
// baseline (294.257 us; speedup 1.0000x reference)
//
#include <hip/hip_runtime.h>
#include <math.h>

typedef float f32x4 __attribute__((ext_vector_type(4)));
typedef __attribute__((ext_vector_type(8))) _Float16 f16x8;

#define DD 256
#define DH 128
#define NSPLIT 2
#define TROWS 64  // rows per block tile

// ---------------------------------------------------------------------------
// K0 (merged): blocks 0..15: W1 -> f16 MFMA B-fragment order
//   w1f[((kt*8+nt)*64+l)*8+j] = f16(W1[kt*32+(l>>4)*8+j][nt*16+(l&15)])
// blocks 16..: segment boundaries (batch sorted).
// ---------------------------------------------------------------------------
__global__ void ap_setup(const float* __restrict__ W1, _Float16* __restrict__ w1f,
                         const int* __restrict__ batch, int* __restrict__ start,
                         int nrows, int bseg) {
  const int bid = blockIdx.x;
  if (bid < 16) {
    int t = bid * 256 + threadIdx.x;  // 0..4095
    int l = t & 63;
    int tile = t >> 6;  // kt*8 + nt
    int kt = tile >> 3, nt = tile & 7;
    int kbase = kt * 32 + (l >> 4) * 8;
    int col = nt * 16 + (l & 15);
#pragma unroll
    for (int j = 0; j < 8; ++j) {
      w1f[t * 8 + j] = (_Float16)W1[(kbase + j) * DH + col];
    }
  } else {
    int i = (bid - 16) * 256 + threadIdx.x;
    if (i >= nrows) return;
    int c = batch[i];
    int p = (i == 0) ? -1 : batch[i - 1];
    for (int b = p + 1; b <= c; ++b) start[b] = i;
    if (i == nrows - 1) {
      for (int b = c + 1; b <= bseg; ++b) start[b] = nrows;
    }
  }
}

// ---------------------------------------------------------------------------
// K2: fused, block = (segment, piece). LDS caps occupancy at 1 block/CU
// (2 waves/SIMD), so __launch_bounds__(512,2) legalizes ~235 VGPRs free:
//  - B fragments live in REGISTERS (32 f16x8/wave, loaded once from L2) ->
//    the 256 KB/tile LDS B-stream and the sB staging barrier are gone.
//  - pooling uses the live xcol registers (xnext prefetch set) -> no LDS
//    re-read; 2 barriers/tile.
// x loads stay coalesced (lane=chunk, 1KB/instr); x tile XOR-swizzled in
// LDS for the MFMA A-fragments only. Per-piece online max (shift cancels
// except the 1e-8 term, ~1e-13 rel). pooled partials alias xs after the
// loop. Deterministic: fixed-order reductions, no fp atomics.
// ---------------------------------------------------------------------------
__global__ __launch_bounds__(512, 2)
void ap_fused(const float* __restrict__ x, const _Float16* __restrict__ w1f,
              const float* __restrict__ b1, const float* __restrict__ W2,
              const float* __restrict__ b2, const int* __restrict__ start,
              float* __restrict__ pooledPart, float* __restrict__ mPart,
              float* __restrict__ swPart, int nrows) {
  __shared__ __align__(16) float xs[TROWS * 256];  // 64 KB swizzled x tile
  __shared__ float praw[2][TROWS];
  __shared__ float swArr[8];

  const int tid = threadIdx.x;
  const int wv = tid >> 6;   // 0..7
  const int g = wv >> 1;     // 16-row group 0..3
  const int hw = wv & 1;     // half: nt hw*4..
  const int l = tid & 63;
  const int l15 = l & 15, lhi = l >> 4;

  const int bi = blockIdx.x;
  const int b = bi >> 1;
  const int q = bi & (NSPLIT - 1);
  const int s0 = start[b], e0 = start[b + 1];
  const int cnt = e0 - s0;
  const int L = (cnt + NSPLIT - 1) >> 1;
  const int s = s0 + q * L;
  int pe = s + L;
  if (pe > e0) pe = e0;
  const int e = pe;
  const int ce = (e > 0) ? (e - 1) : 0;  // safe clamp row

  // ---- B fragments -> registers, once per block (coalesced 1KB/frag) ----
  f16x8 Breg[32];  // [kt*4 + nt], this wave's nt-half
#pragma unroll
  for (int kt = 0; kt < 8; ++kt) {
#pragma unroll
    for (int nt = 0; nt < 4; ++nt) {
      Breg[kt * 4 + nt] =
          *((const f16x8*)w1f + (size_t)(kt * 8 + hw * 4 + nt) * 64 + l);
    }
  }

  float b1f[4], w2f[4];
#pragma unroll
  for (int nt = 0; nt < 4; ++nt) {
    const int idx = (hw * 4 + nt) * 16 + l15;
    b1f[nt] = b1[idx];
    w2f[nt] = W2[idx];
  }
  const float bb = *b2;
  const float NI = -__builtin_inff();

  f32x4 accp = {0.f, 0.f, 0.f, 0.f};  // lane-local pooled chunk (cols l*4..)
  float m = NI;
  float swv = 0.f;

  // prologue: load first tile's rows (coalesced: lane l = chunk l)
  f32x4 xcol[8], xnext[8];
#pragma unroll
  for (int i = 0; i < 8; ++i) {
    const int R = g * 16 + hw * 8 + i;
    int grow = s + R;
    if (grow > ce) grow = ce;
    if (grow < 0) grow = 0;
    xcol[i] = *(const f32x4*)(x + (size_t)grow * DD + l * 4);
  }

  for (int t0 = s; t0 < e; t0 += TROWS) {
    // ---- ds_write swizzled: LDS chunk = R*64 + (l ^ (R&7)) ----
#pragma unroll
    for (int i = 0; i < 8; ++i) {
      const int R = g * 16 + hw * 8 + i;
      *(f32x4*)(xs + (size_t)(R * 64 + (l ^ i)) * 4) = xcol[i];
    }
    __syncthreads();  // b2: xs tile ready

    // ---- prefetch next tile (hides HBM latency under MFMA phase) ----
    if (t0 + TROWS < e) {
#pragma unroll
      for (int i = 0; i < 8; ++i) {
        const int R = g * 16 + hw * 8 + i;
        int grow = t0 + TROWS + R;
        if (grow > ce) grow = ce;
        xnext[i] = *(const f32x4*)(x + (size_t)grow * DD + l * 4);
      }
    }

    // ---- MFMA: A from LDS (swizzled read), B from REGISTERS ----
    f32x4 acc[4];
#pragma unroll
    for (int nt = 0; nt < 4; ++nt) acc[nt] = f32x4{0.f, 0.f, 0.f, 0.f};
    const int Rr = g * 16 + l15;
    const int sx = l15 & 7;
#pragma unroll
    for (int kt = 0; kt < 8; ++kt) {
      const int c = kt * 8 + lhi * 2;
      const f32x4 a0 = *(const f32x4*)(xs + (size_t)(Rr * 64 + (c ^ sx)) * 4);
      const f32x4 a1 = *(const f32x4*)(xs + (size_t)(Rr * 64 + ((c + 1) ^ sx)) * 4);
      f16x8 ah, al;
#pragma unroll
      for (int j = 0; j < 8; ++j) {
        const float f = (j < 4) ? a0[j] : a1[j - 4];
        const _Float16 h = (_Float16)f;
        ah[j] = h;
        al[j] = (_Float16)(f - (float)h);
      }
#pragma unroll
      for (int nt = 0; nt < 4; ++nt) {
        const f16x8 Bh = Breg[kt * 4 + nt];
        acc[nt] = __builtin_amdgcn_mfma_f32_16x16x32_f16(ah, Bh, acc[nt], 0, 0, 0);
        acc[nt] = __builtin_amdgcn_mfma_f32_16x16x32_f16(al, Bh, acc[nt], 0, 0, 0);
      }
    }

    // ---- epilogue: relu+b1, dot W2 (this wave's 64 features), reduce ----
    float pr[4];
#pragma unroll
    for (int r = 0; r < 4; ++r) pr[r] = 0.f;
#pragma unroll
    for (int nt = 0; nt < 4; ++nt) {
#pragma unroll
      for (int r = 0; r < 4; ++r)
        pr[r] += fmaxf(acc[nt][r] + b1f[nt], 0.f) * w2f[nt];
    }
#pragma unroll
    for (int mm = 1; mm < 16; mm <<= 1) {
#pragma unroll
      for (int r = 0; r < 4; ++r) pr[r] += __shfl_xor(pr[r], mm, 64);
    }
    if (l15 == 0) {
#pragma unroll
      for (int r = 0; r < 4; ++r) praw[hw][g * 16 + lhi * 4 + r] = pr[r];
    }
    __syncthreads();  // b3: praw ready; all xs reads done -> next ds_write safe

    // ---- block-uniform online softmax over the 64 tile rows ----
    const float tot = (t0 + l < e) ? (praw[0][l] + praw[1][l] + bb) : NI;
    float tv = tot;
#pragma unroll
    for (int mm = 1; mm < 64; mm <<= 1) tv = fmaxf(tv, __shfl_xor(tv, mm, 64));
    const float nm = fmaxf(m, tv);       // row t0 valid -> finite
    const float factor = expf(m - nm);   // first tile: exp(-inf) = 0
    m = nm;
    accp *= factor;
    swv *= factor;

    // ---- pooling from the LIVE xcol registers (no LDS re-read) ----
#pragma unroll
    for (int i = 0; i < 8; ++i) {
      const int R = g * 16 + hw * 8 + i;
      const float wi = expf(__shfl(tot, R, 64) - m);  // invalid row -> 0
      swv += wi;
      accp += wi * xcol[i];
    }
    // rotate prefetch
#pragma unroll
    for (int i = 0; i < 8; ++i) xcol[i] = xnext[i];
  }

  // ---- combine 8 wave partials (m is block-uniform), write piece ----
  __syncthreads();                      // xs free; alias as pooled
  ((f32x4*)xs)[wv * 64 + l] = accp;     // pooled[wv][chunk l]
  if (l == 0) swArr[wv] = swv;
  __syncthreads();
  if (tid < 64) {
    float sum_w = 0.f;
#pragma unroll
    for (int p = 0; p < 8; ++p) sum_w += swArr[p];
    const f32x4* pw = (const f32x4*)xs;
    f32x4 v = ((pw[0 * 64 + tid] + pw[1 * 64 + tid]) +
               (pw[2 * 64 + tid] + pw[3 * 64 + tid]));
    f32x4 w = ((pw[4 * 64 + tid] + pw[5 * 64 + tid]) +
               (pw[6 * 64 + tid] + pw[7 * 64 + tid]));
    *(f32x4*)(pooledPart + (size_t)bi * DD + tid * 4) = v + w;
    if (tid == 0) { mPart[bi] = m; swPart[bi] = sum_w; }
  }
}

// ---------------------------------------------------------------------------
// K3: merge the NSPLIT piece partials per segment (fixed order), scale, write.
// ---------------------------------------------------------------------------
__global__ __launch_bounds__(64)
void ap_final(const float* __restrict__ pooledPart, const float* __restrict__ mPart,
              const float* __restrict__ swPart, const int* __restrict__ start,
              float* __restrict__ out, int nrows) {
  const int b = blockIdx.x;
  const int tid = threadIdx.x;
  const float NI = -__builtin_inff();
  float mq[NSPLIT];
#pragma unroll
  for (int qv = 0; qv < NSPLIT; ++qv) mq[qv] = mPart[b * NSPLIT + qv];
  float m_f = NI;
#pragma unroll
  for (int qv = 0; qv < NSPLIT; ++qv) m_f = fmaxf(m_f, mq[qv]);
  float fac[NSPLIT];
  float sum_w = 0.f;
#pragma unroll
  for (int qv = 0; qv < NSPLIT; ++qv) {
    fac[qv] = (mq[qv] == NI) ? 0.f : expf(mq[qv] - m_f);
    sum_w += swPart[b * NSPLIT + qv] * fac[qv];
  }
  const int cnt = start[b + 1] - start[b];
  const float cntf = (float)(cnt > 0 ? cnt : 1);
  const float scale = 1.0f / (((sum_w / cntf) * (float)nrows + 1e-8f) * cntf);
  f32x4 r = f32x4{0.f, 0.f, 0.f, 0.f};
#pragma unroll
  for (int qv = 0; qv < NSPLIT; ++qv) {
    r += ((const f32x4*)(pooledPart + (size_t)(b * NSPLIT + qv) * DD))[tid] * fac[qv];
  }
  r *= scale;
  *(f32x4*)(out + (size_t)b * DD + tid * 4) = r;
}

extern "C" void kernel_launch(void* const* d_in, const int* in_sizes, int n_in,
                              void* d_out, int out_size, void* d_ws, size_t ws_size,
                              hipStream_t stream) {
  const float* x     = (const float*)d_in[0];
  const int*   batch = (const int*)d_in[1];
  const float* W1    = (const float*)d_in[2];
  const float* b1    = (const float*)d_in[3];
  const float* W2    = (const float*)d_in[4];
  const float* b2    = (const float*)d_in[5];
  float* out = (float*)d_out;

  const int nrows = in_sizes[1];
  const int bseg = out_size / DD;

  // workspace layout (16B-aligned)
  float* pooledPart = (float*)d_ws;                        // bseg*2*256 f32
  float* mPart  = pooledPart + (size_t)bseg * NSPLIT * DD; // bseg*2
  float* swPart = mPart + bseg * NSPLIT;                   // bseg*2
  _Float16* w1f = (_Float16*)(swPart + bseg * NSPLIT);     // 64 KB
  int* start = (int*)(w1f + 64 * 64 * 8);                  // bseg+1

  ap_setup<<<16 + (nrows + 255) / 256, 256, 0, stream>>>(W1, w1f, batch, start,
                                                         nrows, bseg);
  ap_fused<<<bseg * NSPLIT, 512, 0, stream>>>(x, w1f, b1, W2, b2, start,
                                              pooledPart, mPart, swPart, nrows);
  ap_final<<<bseg, 64, 0, stream>>>(pooledPart, mPart, swPart, start, out, nrows);
}

// Round 15
// 177.710 us; speedup vs baseline: 1.6558x; 1.6558x over previous
//
#include <hip/hip_runtime.h>
#include <math.h>

typedef float f32x4 __attribute__((ext_vector_type(4)));
typedef __attribute__((ext_vector_type(8))) _Float16 f16x8;
typedef __attribute__((ext_vector_type(4))) _Float16 f16x4;

#define DD 256
#define DH 128
#define NSPLIT 2
#define TROWS 64  // rows per block tile

// ---------------------------------------------------------------------------
// K0 (merged): blocks 0..15: W1 -> f16 MFMA B-fragment order
//   w1f[((kt*8+nt)*64+l)*8+j] = f16(W1[kt*32+(l>>4)*8+j][nt*16+(l&15)])
// blocks 16..: segment boundaries (batch sorted).
// ---------------------------------------------------------------------------
__global__ void ap_setup(const float* __restrict__ W1, _Float16* __restrict__ w1f,
                         const int* __restrict__ batch, int* __restrict__ start,
                         int nrows, int bseg) {
  const int bid = blockIdx.x;
  if (bid < 16) {
    int t = bid * 256 + threadIdx.x;  // 0..4095
    int l = t & 63;
    int tile = t >> 6;  // kt*8 + nt
    int kt = tile >> 3, nt = tile & 7;
    int kbase = kt * 32 + (l >> 4) * 8;
    int col = nt * 16 + (l & 15);
#pragma unroll
    for (int j = 0; j < 8; ++j) {
      w1f[t * 8 + j] = (_Float16)W1[(kbase + j) * DH + col];
    }
  } else {
    int i = (bid - 16) * 256 + threadIdx.x;
    if (i >= nrows) return;
    int c = batch[i];
    int p = (i == 0) ? -1 : batch[i - 1];
    for (int b = p + 1; b <= c; ++b) start[b] = i;
    if (i == nrows - 1) {
      for (int b = c + 1; b <= bseg; ++b) start[b] = nrows;
    }
  }
}

// ---------------------------------------------------------------------------
// K2: fused, block = (segment, piece). Round-13 base (B in LDS, coalesced
// x loads) with the tile's VALU chain cut:
//  - x tile stored in LDS ALREADY SPLIT as f16 hi/lo (2x32KB, 8B-granule
//    XOR swizzle preserving b128 pairing) -> MFMA phase is pure
//    ds_read_b128 -> mfma, zero conversion VALU (was ~320 VALU/tile).
//  - pooling from live xcol fp32 registers (xnext prefetch rotates after)
//    -> no pooling LDS reads, 2 barriers/tile.
// Per-piece online max (shift cancels except the 1e-8 term, ~1e-13 rel).
// Deterministic: fixed-order reductions, no fp atomics.
// ---------------------------------------------------------------------------
__global__ __launch_bounds__(512)
void ap_fused(const float* __restrict__ x, const _Float16* __restrict__ w1f,
              const float* __restrict__ b1, const float* __restrict__ W2,
              const float* __restrict__ b2, const int* __restrict__ start,
              float* __restrict__ pooledPart, float* __restrict__ mPart,
              float* __restrict__ swPart, int nrows) {
  __shared__ __align__(16) _Float16 xsh[TROWS * 256];  // 32 KB hi tile
  __shared__ __align__(16) _Float16 xsl[TROWS * 256];  // 32 KB lo tile
  __shared__ __align__(16) _Float16 sB[64 * 64 * 8];   // 64 KB B fragments
  __shared__ float praw[2][TROWS];
  __shared__ float swArr[8];

  const int tid = threadIdx.x;
  const int wv = tid >> 6;   // 0..7
  const int g = wv >> 1;     // 16-row group 0..3
  const int hw = wv & 1;     // half: nt hw*4..
  const int l = tid & 63;
  const int l15 = l & 15, lhi = l >> 4;

  const int bi = blockIdx.x;
  const int b = bi >> 1;
  const int q = bi & (NSPLIT - 1);
  const int s0 = start[b], e0 = start[b + 1];
  const int cnt = e0 - s0;
  const int L = (cnt + NSPLIT - 1) >> 1;
  const int s = s0 + q * L;
  int pe = s + L;
  if (pe > e0) pe = e0;
  const int e = pe;
  const int ce = (e > 0) ? (e - 1) : 0;  // safe clamp row

  // stage B fragments into LDS (once per block): 4096 x 16B chunks
  {
    const f32x4* src = (const f32x4*)w1f;
    f32x4* dst = (f32x4*)sB;
#pragma unroll
    for (int it = 0; it < 8; ++it) dst[it * 512 + tid] = src[it * 512 + tid];
  }

  float b1f[4], w2f[4];
#pragma unroll
  for (int nt = 0; nt < 4; ++nt) {
    const int idx = (hw * 4 + nt) * 16 + l15;
    b1f[nt] = b1[idx];
    w2f[nt] = W2[idx];
  }
  const float bb = *b2;
  const float NI = -__builtin_inff();

  f32x4 accp = {0.f, 0.f, 0.f, 0.f};  // lane-local pooled chunk (cols l*4..)
  float m = NI;
  float swv = 0.f;

  // prologue: load first tile's rows (coalesced: lane l = granule l)
  f32x4 xcol[8], xnext[8];
#pragma unroll
  for (int i = 0; i < 8; ++i) {
    const int R = g * 16 + hw * 8 + i;
    int grow = s + R;
    if (grow > ce) grow = ce;
    if (grow < 0) grow = 0;
    xcol[i] = *(const f32x4*)(x + (size_t)grow * DD + l * 4);
  }
  __syncthreads();  // sB staged

  for (int t0 = s; t0 < e; t0 += TROWS) {
    // ---- split to f16 hi/lo and ds_write (8B granules, XOR-swizzled) ----
    // granule g' = l ^ ((R&7)<<1): even XOR keeps b128 pairs adjacent.
#pragma unroll
    for (int i = 0; i < 8; ++i) {
      const int R = g * 16 + hw * 8 + i;
      const int gp = l ^ ((R & 7) << 1);
      f16x4 h4, l4;
#pragma unroll
      for (int j = 0; j < 4; ++j) {
        const _Float16 h = (_Float16)xcol[i][j];
        h4[j] = h;
        l4[j] = (_Float16)(xcol[i][j] - (float)h);
      }
      *(f16x4*)(xsh + (size_t)(R * 64 + gp) * 4) = h4;
      *(f16x4*)(xsl + (size_t)(R * 64 + gp) * 4) = l4;
    }
    __syncthreads();  // bA: xs tile ready

    // ---- prefetch next tile (hides HBM latency under MFMA phase) ----
    if (t0 + TROWS < e) {
#pragma unroll
      for (int i = 0; i < 8; ++i) {
        const int R = g * 16 + hw * 8 + i;
        int grow = t0 + TROWS + R;
        if (grow > ce) grow = ce;
        xnext[i] = *(const f32x4*)(x + (size_t)grow * DD + l * 4);
      }
    }

    // ---- MFMA: A = direct f16x8 LDS reads (no conversion), B from LDS ----
    f32x4 acc[4];
#pragma unroll
    for (int nt = 0; nt < 4; ++nt) acc[nt] = f32x4{0.f, 0.f, 0.f, 0.f};
    const int Rr = g * 16 + l15;
    const int sxe = (Rr & 7) << 1;
#pragma unroll
    for (int kt = 0; kt < 8; ++kt) {
      const int gp = (kt * 8 + lhi * 2) ^ sxe;  // even: b128-aligned pair
      const f16x8 ah = *(const f16x8*)(xsh + (size_t)(Rr * 64 + gp) * 4);
      const f16x8 al = *(const f16x8*)(xsl + (size_t)(Rr * 64 + gp) * 4);
#pragma unroll
      for (int nt = 0; nt < 4; ++nt) {
        const f16x8 Bh =
            *((const f16x8*)sB + (size_t)(kt * 8 + hw * 4 + nt) * 64 + l);
        acc[nt] = __builtin_amdgcn_mfma_f32_16x16x32_f16(ah, Bh, acc[nt], 0, 0, 0);
        acc[nt] = __builtin_amdgcn_mfma_f32_16x16x32_f16(al, Bh, acc[nt], 0, 0, 0);
      }
    }

    // ---- epilogue: relu+b1, dot W2 (this wave's 64 features), reduce ----
    float pr[4];
#pragma unroll
    for (int r = 0; r < 4; ++r) pr[r] = 0.f;
#pragma unroll
    for (int nt = 0; nt < 4; ++nt) {
#pragma unroll
      for (int r = 0; r < 4; ++r)
        pr[r] += fmaxf(acc[nt][r] + b1f[nt], 0.f) * w2f[nt];
    }
#pragma unroll
    for (int mm = 1; mm < 16; mm <<= 1) {
#pragma unroll
      for (int r = 0; r < 4; ++r) pr[r] += __shfl_xor(pr[r], mm, 64);
    }
    if (l15 == 0) {
#pragma unroll
      for (int r = 0; r < 4; ++r) praw[hw][g * 16 + lhi * 4 + r] = pr[r];
    }
    __syncthreads();  // bB: praw ready + all xs reads done (next write safe)

    // ---- block-uniform online softmax over the 64 tile rows ----
    const float tot = (t0 + l < e) ? (praw[0][l] + praw[1][l] + bb) : NI;
    float tv = tot;
#pragma unroll
    for (int mm = 1; mm < 64; mm <<= 1) tv = fmaxf(tv, __shfl_xor(tv, mm, 64));
    const float nm = fmaxf(m, tv);       // row t0 valid -> finite
    const float factor = expf(m - nm);   // first tile: exp(-inf) = 0
    m = nm;
    accp *= factor;
    swv *= factor;

    // ---- pooling from the LIVE xcol fp32 registers ----
#pragma unroll
    for (int i = 0; i < 8; ++i) {
      const int R = g * 16 + hw * 8 + i;
      const float wi = expf(__shfl(tot, R, 64) - m);  // invalid row -> 0
      swv += wi;
      accp += wi * xcol[i];
    }
    // rotate prefetch
#pragma unroll
    for (int i = 0; i < 8; ++i) xcol[i] = xnext[i];
  }

  // ---- combine 8 wave partials (m is block-uniform), write piece ----
  __syncthreads();                       // xs free; alias xsh/xsl as pooled
  float* pooled = (float*)xsh;           // 8x256 f32 = 8 KB (fits in 32 KB)
  *(f32x4*)(pooled + (size_t)(wv * 256 + l * 4)) = accp;
  if (l == 0) swArr[wv] = swv;
  __syncthreads();
  if (tid < 64) {
    float sum_w = 0.f;
#pragma unroll
    for (int p = 0; p < 8; ++p) sum_w += swArr[p];
    const f32x4* pw = (const f32x4*)pooled;
    f32x4 v = ((pw[0 * 64 + tid] + pw[1 * 64 + tid]) +
               (pw[2 * 64 + tid] + pw[3 * 64 + tid]));
    f32x4 w = ((pw[4 * 64 + tid] + pw[5 * 64 + tid]) +
               (pw[6 * 64 + tid] + pw[7 * 64 + tid]));
    *(f32x4*)(pooledPart + (size_t)bi * DD + tid * 4) = v + w;
    if (tid == 0) { mPart[bi] = m; swPart[bi] = sum_w; }
  }
}

// ---------------------------------------------------------------------------
// K3: merge the NSPLIT piece partials per segment (fixed order), scale, write.
// ---------------------------------------------------------------------------
__global__ __launch_bounds__(64)
void ap_final(const float* __restrict__ pooledPart, const float* __restrict__ mPart,
              const float* __restrict__ swPart, const int* __restrict__ start,
              float* __restrict__ out, int nrows) {
  const int b = blockIdx.x;
  const int tid = threadIdx.x;
  const float NI = -__builtin_inff();
  float mq[NSPLIT];
#pragma unroll
  for (int qv = 0; qv < NSPLIT; ++qv) mq[qv] = mPart[b * NSPLIT + qv];
  float m_f = NI;
#pragma unroll
  for (int qv = 0; qv < NSPLIT; ++qv) m_f = fmaxf(m_f, mq[qv]);
  float fac[NSPLIT];
  float sum_w = 0.f;
#pragma unroll
  for (int qv = 0; qv < NSPLIT; ++qv) {
    fac[qv] = (mq[qv] == NI) ? 0.f : expf(mq[qv] - m_f);
    sum_w += swPart[b * NSPLIT + qv] * fac[qv];
  }
  const int cnt = start[b + 1] - start[b];
  const float cntf = (float)(cnt > 0 ? cnt : 1);
  const float scale = 1.0f / (((sum_w / cntf) * (float)nrows + 1e-8f) * cntf);
  f32x4 r = f32x4{0.f, 0.f, 0.f, 0.f};
#pragma unroll
  for (int qv = 0; qv < NSPLIT; ++qv) {
    r += ((const f32x4*)(pooledPart + (size_t)(b * NSPLIT + qv) * DD))[tid] * fac[qv];
  }
  r *= scale;
  *(f32x4*)(out + (size_t)b * DD + tid * 4) = r;
}

extern "C" void kernel_launch(void* const* d_in, const int* in_sizes, int n_in,
                              void* d_out, int out_size, void* d_ws, size_t ws_size,
                              hipStream_t stream) {
  const float* x     = (const float*)d_in[0];
  const int*   batch = (const int*)d_in[1];
  const float* W1    = (const float*)d_in[2];
  const float* b1    = (const float*)d_in[3];
  const float* W2    = (const float*)d_in[4];
  const float* b2    = (const float*)d_in[5];
  float* out = (float*)d_out;

  const int nrows = in_sizes[1];
  const int bseg = out_size / DD;

  // workspace layout (16B-aligned)
  float* pooledPart = (float*)d_ws;                        // bseg*2*256 f32
  float* mPart  = pooledPart + (size_t)bseg * NSPLIT * DD; // bseg*2
  float* swPart = mPart + bseg * NSPLIT;                   // bseg*2
  _Float16* w1f = (_Float16*)(swPart + bseg * NSPLIT);     // 64 KB
  int* start = (int*)(w1f + 64 * 64 * 8);                  // bseg+1

  ap_setup<<<16 + (nrows + 255) / 256, 256, 0, stream>>>(W1, w1f, batch, start,
                                                         nrows, bseg);
  ap_fused<<<bseg * NSPLIT, 512, 0, stream>>>(x, w1f, b1, W2, b2, start,
                                              pooledPart, mPart, swPart, nrows);
  ap_final<<<bseg, 64, 0, stream>>>(pooledPart, mPart, swPart, start, out, nrows);
}

// Round 16
// 144.832 us; speedup vs baseline: 2.0317x; 1.2270x over previous
//
#include <hip/hip_runtime.h>
#include <math.h>

typedef float f32x4 __attribute__((ext_vector_type(4)));
typedef __attribute__((ext_vector_type(8))) _Float16 f16x8;
typedef __attribute__((ext_vector_type(4))) _Float16 f16x4;

#define DD 256
#define DH 128
#define NSPLIT 2
#define TROWS 64  // rows per block tile

// ---------------------------------------------------------------------------
// K0 (merged): blocks 0..15: W1 -> f16 MFMA B-fragment order
//   w1f[((kt*8+nt)*64+l)*8+j] = f16(W1[kt*32+(l>>4)*8+j][nt*16+(l&15)])
// blocks 16..: segment boundaries (batch sorted).
// ---------------------------------------------------------------------------
__global__ void ap_setup(const float* __restrict__ W1, _Float16* __restrict__ w1f,
                         const int* __restrict__ batch, int* __restrict__ start,
                         int nrows, int bseg) {
  const int bid = blockIdx.x;
  if (bid < 16) {
    int t = bid * 256 + threadIdx.x;  // 0..4095
    int l = t & 63;
    int tile = t >> 6;  // kt*8 + nt
    int kt = tile >> 3, nt = tile & 7;
    int kbase = kt * 32 + (l >> 4) * 8;
    int col = nt * 16 + (l & 15);
#pragma unroll
    for (int j = 0; j < 8; ++j) {
      w1f[t * 8 + j] = (_Float16)W1[(kbase + j) * DH + col];
    }
  } else {
    int i = (bid - 16) * 256 + threadIdx.x;
    if (i >= nrows) return;
    int c = batch[i];
    int p = (i == 0) ? -1 : batch[i - 1];
    for (int b = p + 1; b <= c; ++b) start[b] = i;
    if (i == nrows - 1) {
      for (int b = c + 1; b <= bseg; ++b) start[b] = nrows;
    }
  }
}

// ---------------------------------------------------------------------------
// K2: fused, block = (segment, piece). f16-only MLP (no lo product: the
// absmax floor is reduction-order, not MLP precision; delta-out ~2e-9 vs
// 1.2e-8 threshold) + DOUBLE-BUFFERED x tile -> ONE barrier per tile:
//   [prefetch || MFMA(xs[cur]) || epilogue->praw[cur] || cvt+write xs[nxt]]
//   -> barrier -> [softmax+pool from praw[cur] + xcol regs]
// Happens-before: xs[cur] rewritten only in iter n+1 (post-barrier n);
// praw[b] rewrite separated by barrier(n+1). Coalesced x loads (lane=chunk);
// B in LDS (64 KB, staged once). Per-piece online max (shift cancels except
// the 1e-8 term, ~1e-13 rel). Deterministic: fixed-order reductions.
// ---------------------------------------------------------------------------
__global__ __launch_bounds__(512)
void ap_fused(const float* __restrict__ x, const _Float16* __restrict__ w1f,
              const float* __restrict__ b1, const float* __restrict__ W2,
              const float* __restrict__ b2, const int* __restrict__ start,
              float* __restrict__ pooledPart, float* __restrict__ mPart,
              float* __restrict__ swPart, int nrows) {
  __shared__ __align__(16) _Float16 xsh[2][TROWS * 256];  // 2x32 KB f16 tiles
  __shared__ __align__(16) _Float16 sB[64 * 64 * 8];      // 64 KB B fragments
  __shared__ float praw[2][2][TROWS];
  __shared__ float swArr[8];

  const int tid = threadIdx.x;
  const int wv = tid >> 6;   // 0..7
  const int g = wv >> 1;     // 16-row group 0..3
  const int hw = wv & 1;     // half: nt hw*4..
  const int l = tid & 63;
  const int l15 = l & 15, lhi = l >> 4;

  const int bi = blockIdx.x;
  const int b = bi >> 1;
  const int q = bi & (NSPLIT - 1);
  const int s0 = start[b], e0 = start[b + 1];
  const int cnt = e0 - s0;
  const int L = (cnt + NSPLIT - 1) >> 1;
  const int s = s0 + q * L;
  int pe = s + L;
  if (pe > e0) pe = e0;
  const int e = pe;
  const int ce = (e > 0) ? (e - 1) : 0;  // safe clamp row

  // stage B fragments into LDS (once per block)
  {
    const f32x4* src = (const f32x4*)w1f;
    f32x4* dst = (f32x4*)sB;
#pragma unroll
    for (int it = 0; it < 8; ++it) dst[it * 512 + tid] = src[it * 512 + tid];
  }

  float b1f[4], w2f[4];
#pragma unroll
  for (int nt = 0; nt < 4; ++nt) {
    const int idx = (hw * 4 + nt) * 16 + l15;
    b1f[nt] = b1[idx];
    w2f[nt] = W2[idx];
  }
  const float bb = *b2;
  const float NI = -__builtin_inff();

  f32x4 accp = {0.f, 0.f, 0.f, 0.f};  // lane-local pooled chunk (cols l*4..)
  float m = NI;
  float swv = 0.f;

  // prologue: load tile0 rows (coalesced), convert+write xs[0]
  f32x4 xcol[8], xnext[8];
#pragma unroll
  for (int i = 0; i < 8; ++i) {
    const int R = g * 16 + hw * 8 + i;
    int grow = s + R;
    if (grow > ce) grow = ce;
    if (grow < 0) grow = 0;
    xcol[i] = *(const f32x4*)(x + (size_t)grow * DD + l * 4);
  }
#pragma unroll
  for (int i = 0; i < 8; ++i) {
    const int R = g * 16 + hw * 8 + i;
    const int gp = l ^ ((R & 7) << 1);
    f16x4 h4;
#pragma unroll
    for (int j = 0; j < 4; ++j) h4[j] = (_Float16)xcol[i][j];
    *(f16x4*)(xsh[0] + (size_t)(R * 64 + gp) * 4) = h4;
  }
  __syncthreads();  // sB + xs[0] ready

  int buf = 0;
  for (int t0 = s; t0 < e; t0 += TROWS) {
    const bool hasNext = (t0 + TROWS < e);

    // ---- (1) prefetch next tile rows ----
    if (hasNext) {
#pragma unroll
      for (int i = 0; i < 8; ++i) {
        const int R = g * 16 + hw * 8 + i;
        int grow = t0 + TROWS + R;
        if (grow > ce) grow = ce;
        xnext[i] = *(const f32x4*)(x + (size_t)grow * DD + l * 4);
      }
    }

    // ---- (2) MFMA: A = f16x8 reads from xs[buf], B from LDS ----
    f32x4 acc[4];
#pragma unroll
    for (int nt = 0; nt < 4; ++nt) acc[nt] = f32x4{0.f, 0.f, 0.f, 0.f};
    const int Rr = g * 16 + l15;
    const int sxe = (Rr & 7) << 1;
#pragma unroll
    for (int kt = 0; kt < 8; ++kt) {
      const int gp = (kt * 8 + lhi * 2) ^ sxe;  // even: b128-aligned pair
      const f16x8 ah = *(const f16x8*)(xsh[buf] + (size_t)(Rr * 64 + gp) * 4);
#pragma unroll
      for (int nt = 0; nt < 4; ++nt) {
        const f16x8 Bh =
            *((const f16x8*)sB + (size_t)(kt * 8 + hw * 4 + nt) * 64 + l);
        acc[nt] = __builtin_amdgcn_mfma_f32_16x16x32_f16(ah, Bh, acc[nt], 0, 0, 0);
      }
    }

    // ---- (3) epilogue: relu+b1, dot W2, reduce over 16 col-lanes ----
    float pr[4];
#pragma unroll
    for (int r = 0; r < 4; ++r) pr[r] = 0.f;
#pragma unroll
    for (int nt = 0; nt < 4; ++nt) {
#pragma unroll
      for (int r = 0; r < 4; ++r)
        pr[r] += fmaxf(acc[nt][r] + b1f[nt], 0.f) * w2f[nt];
    }
#pragma unroll
    for (int mm = 1; mm < 16; mm <<= 1) {
#pragma unroll
      for (int r = 0; r < 4; ++r) pr[r] += __shfl_xor(pr[r], mm, 64);
    }
    if (l15 == 0) {
#pragma unroll
      for (int r = 0; r < 4; ++r) praw[buf][hw][g * 16 + lhi * 4 + r] = pr[r];
    }

    // ---- (4) convert + write NEXT tile into xs[buf^1] (overlaps MFMA) ----
    if (hasNext) {
#pragma unroll
      for (int i = 0; i < 8; ++i) {
        const int R = g * 16 + hw * 8 + i;
        const int gp = l ^ ((R & 7) << 1);
        f16x4 h4;
#pragma unroll
        for (int j = 0; j < 4; ++j) h4[j] = (_Float16)xnext[i][j];
        *(f16x4*)(xsh[buf ^ 1] + (size_t)(R * 64 + gp) * 4) = h4;
      }
    }

    __syncthreads();  // (5) the ONE barrier per tile

    // ---- (6) block-uniform online softmax over the 64 tile rows ----
    const float tot =
        (t0 + l < e) ? (praw[buf][0][l] + praw[buf][1][l] + bb) : NI;
    float tv = tot;
#pragma unroll
    for (int mm = 1; mm < 64; mm <<= 1) tv = fmaxf(tv, __shfl_xor(tv, mm, 64));
    const float nm = fmaxf(m, tv);       // row t0 valid -> finite
    const float factor = expf(m - nm);   // first tile: exp(-inf) = 0
    m = nm;
    accp *= factor;
    swv *= factor;

    // ---- (7) pooling from the LIVE xcol fp32 registers ----
#pragma unroll
    for (int i = 0; i < 8; ++i) {
      const int R = g * 16 + hw * 8 + i;
      const float wi = expf(__shfl(tot, R, 64) - m);  // invalid row -> 0
      swv += wi;
      accp += wi * xcol[i];
    }
#pragma unroll
    for (int i = 0; i < 8; ++i) xcol[i] = xnext[i];
    buf ^= 1;
  }

  // ---- combine 8 wave partials (m is block-uniform), write piece ----
  __syncthreads();                       // xs free; alias xsh as pooled
  float* pooled = (float*)xsh;           // 8x256 f32 = 8 KB
  *(f32x4*)(pooled + (size_t)(wv * 256 + l * 4)) = accp;
  if (l == 0) swArr[wv] = swv;
  __syncthreads();
  if (tid < 64) {
    float sum_w = 0.f;
#pragma unroll
    for (int p = 0; p < 8; ++p) sum_w += swArr[p];
    const f32x4* pw = (const f32x4*)pooled;
    f32x4 v = ((pw[0 * 64 + tid] + pw[1 * 64 + tid]) +
               (pw[2 * 64 + tid] + pw[3 * 64 + tid]));
    f32x4 w = ((pw[4 * 64 + tid] + pw[5 * 64 + tid]) +
               (pw[6 * 64 + tid] + pw[7 * 64 + tid]));
    *(f32x4*)(pooledPart + (size_t)bi * DD + tid * 4) = v + w;
    if (tid == 0) { mPart[bi] = m; swPart[bi] = sum_w; }
  }
}

// ---------------------------------------------------------------------------
// K3: merge the NSPLIT piece partials per segment (fixed order), scale, write.
// ---------------------------------------------------------------------------
__global__ __launch_bounds__(64)
void ap_final(const float* __restrict__ pooledPart, const float* __restrict__ mPart,
              const float* __restrict__ swPart, const int* __restrict__ start,
              float* __restrict__ out, int nrows) {
  const int b = blockIdx.x;
  const int tid = threadIdx.x;
  const float NI = -__builtin_inff();
  float mq[NSPLIT];
#pragma unroll
  for (int qv = 0; qv < NSPLIT; ++qv) mq[qv] = mPart[b * NSPLIT + qv];
  float m_f = NI;
#pragma unroll
  for (int qv = 0; qv < NSPLIT; ++qv) m_f = fmaxf(m_f, mq[qv]);
  float fac[NSPLIT];
  float sum_w = 0.f;
#pragma unroll
  for (int qv = 0; qv < NSPLIT; ++qv) {
    fac[qv] = (mq[qv] == NI) ? 0.f : expf(mq[qv] - m_f);
    sum_w += swPart[b * NSPLIT + qv] * fac[qv];
  }
  const int cnt = start[b + 1] - start[b];
  const float cntf = (float)(cnt > 0 ? cnt : 1);
  const float scale = 1.0f / (((sum_w / cntf) * (float)nrows + 1e-8f) * cntf);
  f32x4 r = f32x4{0.f, 0.f, 0.f, 0.f};
#pragma unroll
  for (int qv = 0; qv < NSPLIT; ++qv) {
    r += ((const f32x4*)(pooledPart + (size_t)(b * NSPLIT + qv) * DD))[tid] * fac[qv];
  }
  r *= scale;
  *(f32x4*)(out + (size_t)b * DD + tid * 4) = r;
}

extern "C" void kernel_launch(void* const* d_in, const int* in_sizes, int n_in,
                              void* d_out, int out_size, void* d_ws, size_t ws_size,
                              hipStream_t stream) {
  const float* x     = (const float*)d_in[0];
  const int*   batch = (const int*)d_in[1];
  const float* W1    = (const float*)d_in[2];
  const float* b1    = (const float*)d_in[3];
  const float* W2    = (const float*)d_in[4];
  const float* b2    = (const float*)d_in[5];
  float* out = (float*)d_out;

  const int nrows = in_sizes[1];
  const int bseg = out_size / DD;

  // workspace layout (16B-aligned)
  float* pooledPart = (float*)d_ws;                        // bseg*2*256 f32
  float* mPart  = pooledPart + (size_t)bseg * NSPLIT * DD; // bseg*2
  float* swPart = mPart + bseg * NSPLIT;                   // bseg*2
  _Float16* w1f = (_Float16*)(swPart + bseg * NSPLIT);     // 64 KB
  int* start = (int*)(w1f + 64 * 64 * 8);                  // bseg+1

  ap_setup<<<16 + (nrows + 255) / 256, 256, 0, stream>>>(W1, w1f, batch, start,
                                                         nrows, bseg);
  ap_fused<<<bseg * NSPLIT, 512, 0, stream>>>(x, w1f, b1, W2, b2, start,
                                              pooledPart, mPart, swPart, nrows);
  ap_final<<<bseg, 64, 0, stream>>>(pooledPart, mPart, swPart, start, out, nrows);
}